// Round 14
// baseline (1043.383 us; speedup 1.0000x reference)
//
#include <hip/hip_runtime.h>

typedef __attribute__((ext_vector_type(8))) short short8;
typedef __attribute__((ext_vector_type(16))) float f32x16;
typedef __attribute__((ext_vector_type(4))) float float4v;
typedef __attribute__((ext_vector_type(4))) unsigned u32x4;
typedef __attribute__((ext_vector_type(4))) unsigned short ushort4v;
typedef unsigned short u16;

#define MFMA32(a, b, c) __builtin_amdgcn_mfma_f32_32x32x16_bf16((a), (b), (c), 0, 0, 0)

#define W_ 128
#define C_ 256
#define X_LD 136     // x chunk [128][136] bf16 in region A
#define VT_LD 136    // vT half [128][136] over region A
#define QK_LD 36     // q,k [128][36] in region C (32 data + 4 pad)

__device__ __forceinline__ u16 f2bf(float f) {
    unsigned u = __builtin_bit_cast(unsigned, f);
    u += 0x7fffu + ((u >> 16) & 1u);   // RNE
    return (u16)(u >> 16);
}

__device__ __forceinline__ f32x16 zero16() {
    f32x16 z;
#pragma unroll
    for (int i = 0; i < 16; ++i) z[i] = 0.f;
    return z;
}

// raw barrier: drain LDS ops (global stores keep flowing), fence scheduler both sides
__device__ __forceinline__ void wg_barrier() {
    asm volatile("s_waitcnt lgkmcnt(0)" ::: "memory");
    __builtin_amdgcn_sched_barrier(0);
    __builtin_amdgcn_s_barrier();
    __builtin_amdgcn_sched_barrier(0);
}

// Pack weights into MFMA fragment order (bf16), 16 slabs x 10 frags x 512 u16:
// pack[ks*5120 + f*512 + l*8 + j] = w[ks*16 + (l>>5)*8 + j][col(f, l&31)]
// f=0: wq, f=1: wk, f=2+ci: wv col = ci*32 + (l&31). Same layout serves B-frags
// (q,k: col=lane&31) and A-frags (vT: row=lane&31) by A/B symmetry.
__global__ __launch_bounds__(256) void prep_pack(const float* __restrict__ wq,
                                                 const float* __restrict__ wk,
                                                 const float* __restrict__ wv,
                                                 u16* __restrict__ pack) {
    int t = blockIdx.x * 256 + threadIdx.x;   // 0 .. 81919
    int j = t & 7;
    int l = (t >> 3) & 63;
    int g = t >> 9;            // 0..159
    int f = g % 10;
    int ks = g / 10;           // 0..15
    int k = ks * 16 + ((l >> 5) << 3) + j;
    int c = l & 31;
    float w;
    if (f == 0)      w = wq[k * 32 + c];
    else if (f == 1) w = wk[k * 32 + c];
    else             w = wv[k * 256 + (f - 2) * 32 + c];
    pack[t] = f2bf(w);
}

// One block per (b,h) slice. 4 waves x 32 rows, 32x32x16 MFMA.
// LDS diet (R14): ALL weights stream from L2 to registers; LDS = x-chunk/vT
// (34816 B) + q,k (18432 B) = 53248 B -> 3 blocks/CU, 12 waves/CU.
// Scores swapped (sT = K@Q^T) -> softmax + p fully in registers.
// NOTE rule #20: every register-array index must be compile-time constant.
__global__ __launch_bounds__(256, 3) void attn_fused(
        const float* __restrict__ x,
        const u16* __restrict__ pack,
        const float* __restrict__ bq, const float* __restrict__ bk,
        const float* __restrict__ bv,
        float* __restrict__ out) {
    __shared__ u16 uA[17408];   // x chunk -> vT half0 -> vT half1
    __shared__ u16 uC[9216];    // q [0,4608), k [4608,9216)

    const int slice = blockIdx.x;
    const int tid = threadIdx.x;
    const int lane = tid & 63;
    const int wid = tid >> 6;          // 0..3
    const int lm = lane & 31;
    const int l5 = lane >> 5;          // 0/1
    const int rowbase = wid * 32;      // wave owns w-rows [rowbase, rowbase+32)
    const float* xs = x + (size_t)slice * (W_ * C_);

    // weight streams (all L2-hot after first block):
    const u16* qkw = pack + lane * 8;                          // + ks*5120 (+512 for k)
    const u16* vw0 = pack + (size_t)(2 + wid) * 512 + lane * 8;      // v tile wid
    const u16* vw1 = pack + (size_t)(2 + wid + 4) * 512 + lane * 8;  // v tile wid+4

    const int r0 = tid >> 5;           // 0..7
    const int colx = (tid & 31) * 4;   // 0..124

    f32x16 qa = zero16();
    f32x16 ka = zero16();
    f32x16 vac0[4], vac1[4];
#pragma unroll
    for (int nn = 0; nn < 4; ++nn) { vac0[nn] = zero16(); vac1[nn] = zero16(); }

    // ---------------- Projections: stream x in two K=128 chunks ----------------
    for (int c = 0; c < 2; ++c) {
        if (c == 1) wg_barrier();   // all chunk-0 uA reads done before restage
        {   // stage x[:, c*128 .. +128) -> uA bf16
#pragma unroll
            for (int p = 0; p < 16; ++p) {
                int row = p * 8 + r0;
                float4v xv = *reinterpret_cast<const float4v*>(xs + row * C_ + c * 128 + colx);
                ushort4v b4;
                b4[0] = f2bf(xv[0]); b4[1] = f2bf(xv[1]);
                b4[2] = f2bf(xv[2]); b4[3] = f2bf(xv[3]);
                *reinterpret_cast<ushort4v*>(&uA[row * X_LD + colx]) = b4;
            }
        }
        __syncthreads();   // x chunk visible

        // v-weight software pipeline, depth 2 (proven R9 structure)
        short8 wf0[4], wf1[4];
        wf0[0] = *reinterpret_cast<const short8*>(vw0 + (size_t)(c * 8 + 0) * 5120);
        wf1[0] = *reinterpret_cast<const short8*>(vw1 + (size_t)(c * 8 + 0) * 5120);
        wf0[1] = *reinterpret_cast<const short8*>(vw0 + (size_t)(c * 8 + 1) * 5120);
        wf1[1] = *reinterpret_cast<const short8*>(vw1 + (size_t)(c * 8 + 1) * 5120);
        // qk-weight pipeline, depth 2
        short8 qw[2], kw[2];
        qw[0] = *reinterpret_cast<const short8*>(qkw + (size_t)(c * 8 + 0) * 5120);
        kw[0] = *reinterpret_cast<const short8*>(qkw + (size_t)(c * 8 + 0) * 5120 + 512);

#pragma unroll
        for (int kt = 0; kt < 8; ++kt) {
            const int ks = c * 8 + kt;
            if (kt < 6) {
                wf0[(kt + 2) & 3] = *reinterpret_cast<const short8*>(vw0 + (size_t)(ks + 2) * 5120);
                wf1[(kt + 2) & 3] = *reinterpret_cast<const short8*>(vw1 + (size_t)(ks + 2) * 5120);
            }
            if (kt < 7) {
                qw[(kt + 1) & 1] = *reinterpret_cast<const short8*>(qkw + (size_t)(ks + 1) * 5120);
                kw[(kt + 1) & 1] = *reinterpret_cast<const short8*>(qkw + (size_t)(ks + 1) * 5120 + 512);
            }
            // x fragments: rows nn*32+lm, k-slice kt*16 + l5*8 (A/B layouts coincide)
            short8 xf[4];
#pragma unroll
            for (int nn = 0; nn < 4; ++nn)
                xf[nn] = *reinterpret_cast<const short8*>(&uA[(nn * 32 + lm) * X_LD + kt * 16 + l5 * 8]);
            // aqk: separate LDS load (compile-time addressing; do NOT index xf[wid])
            short8 aqk = *reinterpret_cast<const short8*>(&uA[(rowbase + lm) * X_LD + kt * 16 + l5 * 8]);
            qa = MFMA32(aqk, qw[kt & 1], qa);
            ka = MFMA32(aqk, kw[kt & 1], ka);
#pragma unroll
            for (int nn = 0; nn < 4; ++nn) {
                vac0[nn] = MFMA32(wf0[kt & 3], xf[nn], vac0[nn]);   // D[vcol][w'] = vT
                vac1[nn] = MFMA32(wf1[kt & 3], xf[nn], vac1[nn]);
            }
        }
    }
    wg_barrier();   // all x reads done before uA is repurposed

    // ---------------- q,k (+bias) -> region C ; vT half0 (+bias) -> region A ----------------
    {
        float bqv = bq[lm];
        float bkv = bk[lm];
#pragma unroll
        for (int e = 0; e < 16; ++e) {
            int row = rowbase + (e & 3) + 8 * (e >> 2) + 4 * l5;
            uC[row * QK_LD + lm] = f2bf(qa[e] + bqv);
            uC[4608 + row * QK_LD + lm] = f2bf(ka[e] + bkv);
        }
    }
#pragma unroll
    for (int e = 0; e < 16; ++e) {
        int cl = (e & 3) + 8 * (e >> 2) + 4 * l5;     // v-col within tile
        float bvv = bv[wid * 32 + cl];
#pragma unroll
        for (int nn = 0; nn < 4; ++nn)
            uA[(wid * 32 + cl) * VT_LD + nn * 32 + lm] = f2bf(vac0[nn][e] + bvv);
    }
    wg_barrier();   // q,k,vT0 visible

    // ---------------- scores (swapped): sT = K @ Q^T ----------------
    f32x16 sT[4];
#pragma unroll
    for (int c2 = 0; c2 < 4; ++c2) sT[c2] = zero16();
#pragma unroll
    for (int ktd = 0; ktd < 2; ++ktd) {
        short8 qf = *reinterpret_cast<const short8*>(&uC[(rowbase + lm) * QK_LD + ktd * 16 + l5 * 8]);
#pragma unroll
        for (int c2 = 0; c2 < 4; ++c2) {
            short8 kf = *reinterpret_cast<const short8*>(&uC[4608 + (c2 * 32 + lm) * QK_LD + ktd * 16 + l5 * 8]);
            sT[c2] = MFMA32(kf, qf, sT[c2]);
        }
    }
    // lane (lm,l5) holds s[w=rowbase+lm][k' = c2*32 + (e&3)+8*(e>>2)+4*l5];
    // partner lane^32 holds the complementary 64 k' values.

    // ---------------- softmax fully in registers (lane-pair reduce) ----------------
    float m = sT[0][0];
#pragma unroll
    for (int c2 = 0; c2 < 4; ++c2)
#pragma unroll
        for (int e = 0; e < 16; ++e) m = fmaxf(m, sT[c2][e]);
    m = fmaxf(m, __shfl_xor(m, 32));
    float sum = 0.f;
#pragma unroll
    for (int c2 = 0; c2 < 4; ++c2)
#pragma unroll
        for (int e = 0; e < 16; ++e) {
            float v = __expf(sT[c2][e] - m);
            sT[c2][e] = v;
            sum += v;
        }
    sum += __shfl_xor(sum, 32);
    const float inv = 1.0f / sum;

    // ---------------- p -> PV A-frags via bf16 pack + lane^32 exchange ----------------
    short8 pf[8];
#pragma unroll
    for (int c2 = 0; c2 < 4; ++c2) {
        unsigned bpk[8];
#pragma unroll
        for (int i = 0; i < 8; ++i)
            bpk[i] = (unsigned)f2bf(sT[c2][2 * i] * inv) |
                     ((unsigned)f2bf(sT[c2][2 * i + 1] * inv) << 16);
#pragma unroll
        for (int hh = 0; hh < 2; ++hh) {
            unsigned s0 = l5 ? bpk[4 * hh + 0] : bpk[4 * hh + 2];
            unsigned s1 = l5 ? bpk[4 * hh + 1] : bpk[4 * hh + 3];
            unsigned t0 = (unsigned)__shfl_xor((int)s0, 32);
            unsigned t1 = (unsigned)__shfl_xor((int)s1, 32);
            union { u32x4 u; short8 s; } fr;
            fr.u[0] = l5 ? t0 : bpk[4 * hh + 0];
            fr.u[1] = l5 ? t1 : bpk[4 * hh + 1];
            fr.u[2] = l5 ? bpk[4 * hh + 2] : t0;
            fr.u[3] = l5 ? bpk[4 * hh + 3] : t1;
            pf[2 * c2 + hh] = fr.s;
        }
    }

    float* os = out + (size_t)slice * (W_ * C_);

    // ---------------- PV half0: out[:, 0:128) ----------------
    f32x16 oc[4];
#pragma unroll
    for (int c2 = 0; c2 < 4; ++c2) oc[c2] = zero16();
#pragma unroll
    for (int kt16 = 0; kt16 < 8; ++kt16) {
#pragma unroll
        for (int c2 = 0; c2 < 4; ++c2) {
            short8 vb = *reinterpret_cast<const short8*>(&uA[(c2 * 32 + lm) * VT_LD + kt16 * 16 + l5 * 8]);
            oc[c2] = MFMA32(pf[kt16], vb, oc[c2]);
        }
    }
    wg_barrier();   // vT0 reads done before vT1 overwrite

    // ---------------- store out half0 ; vT half1 -> region A ----------------
#pragma unroll
    for (int c2 = 0; c2 < 4; ++c2)
#pragma unroll
        for (int e = 0; e < 16; ++e) {
            int row = rowbase + (e & 3) + 8 * (e >> 2) + 4 * l5;
            os[row * C_ + c2 * 32 + lm] = oc[c2][e];
        }
#pragma unroll
    for (int e = 0; e < 16; ++e) {
        int cl = (e & 3) + 8 * (e >> 2) + 4 * l5;
        float bvv = bv[128 + wid * 32 + cl];
#pragma unroll
        for (int nn = 0; nn < 4; ++nn)
            uA[(wid * 32 + cl) * VT_LD + nn * 32 + lm] = f2bf(vac1[nn][e] + bvv);
    }
    wg_barrier();   // vT1 visible (global stores keep draining)

    // ---------------- PV half1: out[:, 128:256) ----------------
#pragma unroll
    for (int c2 = 0; c2 < 4; ++c2) oc[c2] = zero16();
#pragma unroll
    for (int kt16 = 0; kt16 < 8; ++kt16) {
#pragma unroll
        for (int c2 = 0; c2 < 4; ++c2) {
            short8 vb = *reinterpret_cast<const short8*>(&uA[(c2 * 32 + lm) * VT_LD + kt16 * 16 + l5 * 8]);
            oc[c2] = MFMA32(pf[kt16], vb, oc[c2]);
        }
    }
#pragma unroll
    for (int c2 = 0; c2 < 4; ++c2)
#pragma unroll
        for (int e = 0; e < 16; ++e) {
            int row = rowbase + (e & 3) + 8 * (e >> 2) + 4 * l5;
            os[row * C_ + 128 + c2 * 32 + lm] = oc[c2][e];
        }
}

extern "C" void kernel_launch(void* const* d_in, const int* in_sizes, int n_in,
                              void* d_out, int out_size, void* d_ws, size_t ws_size,
                              hipStream_t stream) {
    const float* x  = (const float*)d_in[0];
    const float* wq = (const float*)d_in[1];
    const float* bq = (const float*)d_in[2];
    const float* wk = (const float*)d_in[3];
    const float* bk = (const float*)d_in[4];
    const float* wv = (const float*)d_in[5];
    const float* bv = (const float*)d_in[6];
    float* out = (float*)d_out;
    u16* pack = (u16*)d_ws;   // 16 slabs x 5120 u16 = 160 KB

    prep_pack<<<320, 256, 0, stream>>>(wq, wk, wv, pack);
    attn_fused<<<2048, 256, 0, stream>>>(x, pack, bq, bk, bv, out);
}

// Round 15
// 133.538 us; speedup vs baseline: 7.8134x; 7.8134x over previous
//
#include <hip/hip_runtime.h>

typedef __attribute__((ext_vector_type(8))) short short8;
typedef __attribute__((ext_vector_type(16))) float f32x16;
typedef __attribute__((ext_vector_type(4))) float float4v;
typedef __attribute__((ext_vector_type(4))) unsigned u32x4;
typedef __attribute__((ext_vector_type(4))) unsigned short ushort4v;
typedef unsigned short u16;

#define MFMA32(a, b, c) __builtin_amdgcn_mfma_f32_32x32x16_bf16((a), (b), (c), 0, 0, 0)

#define W_ 128
#define C_ 256
#define X_LD 72      // x chunk [128][72] bf16 (64 data + 8 pad) in region A
#define VT_LD 136    // vT half [128][136] over region A
#define QK_LD 40     // q,k [128][40] in region C

__device__ __forceinline__ u16 f2bf(float f) {
    unsigned u = __builtin_bit_cast(unsigned, f);
    u += 0x7fffu + ((u >> 16) & 1u);   // RNE
    return (u16)(u >> 16);
}

__device__ __forceinline__ f32x16 zero16() {
    f32x16 z;
#pragma unroll
    for (int i = 0; i < 16; ++i) z[i] = 0.f;
    return z;
}

// global -> LDS direct copy, 16B per lane (dst wave-uniform, src per-lane).
__device__ __forceinline__ void gll16(const u16* g, const u16* l) {
    auto s = (const __attribute__((address_space(1))) unsigned*)((uintptr_t)g);
    auto d = (__attribute__((address_space(3))) unsigned*)((unsigned)(uintptr_t)l);
    __builtin_amdgcn_global_load_lds(s, d, 16, 0, 0);
}

// raw barrier: drain LDS ops (global stores keep flowing), fence scheduler both sides
__device__ __forceinline__ void wg_barrier() {
    asm volatile("s_waitcnt lgkmcnt(0)" ::: "memory");
    __builtin_amdgcn_sched_barrier(0);
    __builtin_amdgcn_s_barrier();
    __builtin_amdgcn_sched_barrier(0);
}

// Pack weights into MFMA fragment order (bf16), 16 slabs x 10 frags x 512 u16:
// pack[ks*5120 + f*512 + l*8 + j] = w[ks*16 + (l>>5)*8 + j][col(f, l&31)]
// f=0: wq, f=1: wk, f=2+ci: wv col = ci*32 + (l&31). Same layout serves B-frags
// (q,k: col=lane&31) and A-frags (vT: row=lane&31) by A/B symmetry.
__global__ __launch_bounds__(256) void prep_pack(const float* __restrict__ wq,
                                                 const float* __restrict__ wk,
                                                 const float* __restrict__ wv,
                                                 u16* __restrict__ pack) {
    int t = blockIdx.x * 256 + threadIdx.x;   // 0 .. 81919
    int j = t & 7;
    int l = (t >> 3) & 63;
    int g = t >> 9;            // 0..159
    int f = g % 10;
    int ks = g / 10;           // 0..15
    int k = ks * 16 + ((l >> 5) << 3) + j;
    int c = l & 31;
    float w;
    if (f == 0)      w = wq[k * 32 + c];
    else if (f == 1) w = wk[k * 32 + c];
    else             w = wv[k * 256 + (f - 2) * 32 + c];
    pack[t] = f2bf(w);
}

// One block per (b,h) slice. 4 waves x 32 rows, 32x32x16 MFMA.
// LDS: regA 34816 (x chunk [128][72] -> vT halves [128][136]) + regC 32768
// (qk weight frags -> q,k) = 67584 B -> 2 blocks/CU (register-capped anyway:
// ~290 regs/wave incl. accumulators means 2 waves/SIMD is the hard ceiling, R14).
// R15: 4 x 64-col chunks; next chunk's 8 float4 loads (32 VGPR) issued BEFORE
// compute of current chunk -> HBM latency hides under 40 MFMAs (T3 2-phase).
// Scores swapped (sT = K@Q^T) -> softmax + p fully in registers.
// NOTE rule #20: every register-array index must be compile-time constant.
__global__ __launch_bounds__(256, 2) void attn_fused(
        const float* __restrict__ x,
        const u16* __restrict__ pack,
        const float* __restrict__ bq, const float* __restrict__ bk,
        const float* __restrict__ bv,
        float* __restrict__ out) {
    __shared__ u16 uA[17408];   // x chunk [128][72] -> vT half0 -> vT half1
    __shared__ u16 uC[16384];   // qk weight frags (16384) -> q[0,5120) k[5120,10240)

    const int slice = blockIdx.x;
    const int tid = threadIdx.x;
    const int lane = tid & 63;
    const int wid = tid >> 6;          // 0..3
    const int lm = lane & 31;
    const int l5 = lane >> 5;          // 0/1
    const int rowbase = wid * 32;      // wave owns w-rows [rowbase, rowbase+32)
    const float* xs = x + (size_t)slice * (W_ * C_);

    // v weight streams: wave wid owns v-col tiles {wid, wid+4}
    const u16* vw0 = pack + (size_t)(2 + wid) * 512 + lane * 8;
    const u16* vw1 = pack + (size_t)(2 + wid + 4) * 512 + lane * 8;

    const int r0x = tid >> 4;          // 0..15 (row group for staging)
    const int colx = (tid & 15) * 4;   // 0..60 (float col within 64-chunk)

    f32x16 qa = zero16();
    f32x16 ka = zero16();
    f32x16 vac0[4], vac1[4];
#pragma unroll
    for (int nn = 0; nn < 4; ++nn) { vac0[nn] = zero16(); vac1[nn] = zero16(); }

    // ---- prologue: chunk-0 x loads, qk weights -> uC via gll16, stage chunk 0 ----
    float4v xv[8];
#pragma unroll
    for (int p = 0; p < 8; ++p)
        xv[p] = *reinterpret_cast<const float4v*>(xs + (p * 16 + r0x) * C_ + colx);
#pragma unroll
    for (int i = 0; i < 4; ++i) {
        int ks = wid * 4 + i;
        const u16* gs = pack + (size_t)ks * 5120 + lane * 8;
        gll16(gs, &uC[(ks * 2 + 0) * 512]);
        gll16(gs + 512, &uC[(ks * 2 + 1) * 512]);
    }
#pragma unroll
    for (int p = 0; p < 8; ++p) {
        int row = p * 16 + r0x;
        ushort4v b4;
        b4[0] = f2bf(xv[p][0]); b4[1] = f2bf(xv[p][1]);
        b4[2] = f2bf(xv[p][2]); b4[3] = f2bf(xv[p][3]);
        *reinterpret_cast<ushort4v*>(&uA[row * X_LD + colx]) = b4;
    }
    __syncthreads();   // x0 visible; qk-weight gll landed (full vmcnt drain)

    // v-weight ring, loads 2 slabs ahead (global ks)
    short8 wf0[4], wf1[4];
    wf0[0] = *reinterpret_cast<const short8*>(vw0 + (size_t)0 * 5120);
    wf1[0] = *reinterpret_cast<const short8*>(vw1 + (size_t)0 * 5120);
    wf0[1] = *reinterpret_cast<const short8*>(vw0 + (size_t)1 * 5120);
    wf1[1] = *reinterpret_cast<const short8*>(vw1 + (size_t)1 * 5120);

    // ---------------- Projection: 4 chunks of 64 cols ----------------
#pragma unroll
    for (int c = 0; c < 4; ++c) {
        // T14-lite: issue next chunk's loads before compute (32 VGPR held)
        if (c < 3) {
#pragma unroll
            for (int p = 0; p < 8; ++p)
                xv[p] = *reinterpret_cast<const float4v*>(
                    xs + (p * 16 + r0x) * C_ + (c + 1) * 64 + colx);
        }
        __builtin_amdgcn_sched_barrier(0);   // pin issue point (no sinking below)

        // compute chunk c (kt = 0..3, global ks = c*4+kt)
#pragma unroll
        for (int kt = 0; kt < 4; ++kt) {
            const int ks = c * 4 + kt;
            if (ks < 14) {
                wf0[(ks + 2) & 3] = *reinterpret_cast<const short8*>(vw0 + (size_t)(ks + 2) * 5120);
                wf1[(ks + 2) & 3] = *reinterpret_cast<const short8*>(vw1 + (size_t)(ks + 2) * 5120);
            }
            short8 xf[4];
#pragma unroll
            for (int nn = 0; nn < 4; ++nn)
                xf[nn] = *reinterpret_cast<const short8*>(&uA[(nn * 32 + lm) * X_LD + kt * 16 + l5 * 8]);
            // aqk: separate LDS load (compile-time addressing; do NOT index xf[wid])
            short8 aqk = *reinterpret_cast<const short8*>(&uA[(rowbase + lm) * X_LD + kt * 16 + l5 * 8]);
            short8 bq8 = *reinterpret_cast<const short8*>(&uC[(ks * 2 + 0) * 512 + lane * 8]);
            short8 bk8 = *reinterpret_cast<const short8*>(&uC[(ks * 2 + 1) * 512 + lane * 8]);
            qa = MFMA32(aqk, bq8, qa);
            ka = MFMA32(aqk, bk8, ka);
#pragma unroll
            for (int nn = 0; nn < 4; ++nn) {
                vac0[nn] = MFMA32(wf0[ks & 3], xf[nn], vac0[nn]);   // D[vcol][w'] = vT
                vac1[nn] = MFMA32(wf1[ks & 3], xf[nn], vac1[nn]);
            }
        }

        if (c < 3) {
            wg_barrier();   // all waves done reading x chunk c
#pragma unroll
            for (int p = 0; p < 8; ++p) {
                int row = p * 16 + r0x;
                ushort4v b4;
                b4[0] = f2bf(xv[p][0]); b4[1] = f2bf(xv[p][1]);
                b4[2] = f2bf(xv[p][2]); b4[3] = f2bf(xv[p][3]);
                *reinterpret_cast<ushort4v*>(&uA[row * X_LD + colx]) = b4;
            }
            __syncthreads();   // chunk c+1 visible
        }
    }
    wg_barrier();   // all x/qk-weight reads done before uA/uC are repurposed

    // ---------------- q,k (+bias) -> region C ; vT half0 (+bias) -> region A ----------------
    {
        float bqv = bq[lm];
        float bkv = bk[lm];
#pragma unroll
        for (int e = 0; e < 16; ++e) {
            int row = rowbase + (e & 3) + 8 * (e >> 2) + 4 * l5;
            uC[row * QK_LD + lm] = f2bf(qa[e] + bqv);
            uC[5120 + row * QK_LD + lm] = f2bf(ka[e] + bkv);
        }
    }
#pragma unroll
    for (int e = 0; e < 16; ++e) {
        int cl = (e & 3) + 8 * (e >> 2) + 4 * l5;     // v-col within tile
        float bvv = bv[wid * 32 + cl];
#pragma unroll
        for (int nn = 0; nn < 4; ++nn)
            uA[(wid * 32 + cl) * VT_LD + nn * 32 + lm] = f2bf(vac0[nn][e] + bvv);
    }
    wg_barrier();   // q,k,vT0 visible

    // ---------------- scores (swapped): sT = K @ Q^T ----------------
    f32x16 sT[4];
#pragma unroll
    for (int c2 = 0; c2 < 4; ++c2) sT[c2] = zero16();
#pragma unroll
    for (int ktd = 0; ktd < 2; ++ktd) {
        short8 qf = *reinterpret_cast<const short8*>(&uC[(rowbase + lm) * QK_LD + ktd * 16 + l5 * 8]);
#pragma unroll
        for (int c2 = 0; c2 < 4; ++c2) {
            short8 kf = *reinterpret_cast<const short8*>(&uC[5120 + (c2 * 32 + lm) * QK_LD + ktd * 16 + l5 * 8]);
            sT[c2] = MFMA32(kf, qf, sT[c2]);
        }
    }
    // lane (lm,l5) holds s[w=rowbase+lm][k' = c2*32 + (e&3)+8*(e>>2)+4*l5];
    // partner lane^32 holds the complementary 64 k' values.

    // ---------------- softmax fully in registers (lane-pair reduce) ----------------
    float m = sT[0][0];
#pragma unroll
    for (int c2 = 0; c2 < 4; ++c2)
#pragma unroll
        for (int e = 0; e < 16; ++e) m = fmaxf(m, sT[c2][e]);
    m = fmaxf(m, __shfl_xor(m, 32));
    float sum = 0.f;
#pragma unroll
    for (int c2 = 0; c2 < 4; ++c2)
#pragma unroll
        for (int e = 0; e < 16; ++e) {
            float v = __expf(sT[c2][e] - m);
            sT[c2][e] = v;
            sum += v;
        }
    sum += __shfl_xor(sum, 32);
    const float inv = 1.0f / sum;

    // ---------------- p -> PV A-frags via bf16 pack + lane^32 exchange ----------------
    short8 pf[8];
#pragma unroll
    for (int c2 = 0; c2 < 4; ++c2) {
        unsigned bpk[8];
#pragma unroll
        for (int i = 0; i < 8; ++i)
            bpk[i] = (unsigned)f2bf(sT[c2][2 * i] * inv) |
                     ((unsigned)f2bf(sT[c2][2 * i + 1] * inv) << 16);
#pragma unroll
        for (int hh = 0; hh < 2; ++hh) {
            unsigned s0 = l5 ? bpk[4 * hh + 0] : bpk[4 * hh + 2];
            unsigned s1 = l5 ? bpk[4 * hh + 1] : bpk[4 * hh + 3];
            unsigned t0 = (unsigned)__shfl_xor((int)s0, 32);
            unsigned t1 = (unsigned)__shfl_xor((int)s1, 32);
            union { u32x4 u; short8 s; } fr;
            fr.u[0] = l5 ? t0 : bpk[4 * hh + 0];
            fr.u[1] = l5 ? t1 : bpk[4 * hh + 1];
            fr.u[2] = l5 ? bpk[4 * hh + 2] : t0;
            fr.u[3] = l5 ? bpk[4 * hh + 3] : t1;
            pf[2 * c2 + hh] = fr.s;
        }
    }

    float* os = out + (size_t)slice * (W_ * C_);

    // ---------------- PV half0: out[:, 0:128) ----------------
    f32x16 oc[4];
#pragma unroll
    for (int c2 = 0; c2 < 4; ++c2) oc[c2] = zero16();
#pragma unroll
    for (int kt16 = 0; kt16 < 8; ++kt16) {
#pragma unroll
        for (int c2 = 0; c2 < 4; ++c2) {
            short8 vb = *reinterpret_cast<const short8*>(&uA[(c2 * 32 + lm) * VT_LD + kt16 * 16 + l5 * 8]);
            oc[c2] = MFMA32(pf[kt16], vb, oc[c2]);
        }
    }
    wg_barrier();   // vT0 reads done before vT1 overwrite

    // ---------------- store out half0 ; vT half1 -> region A ----------------
#pragma unroll
    for (int c2 = 0; c2 < 4; ++c2)
#pragma unroll
        for (int e = 0; e < 16; ++e) {
            int row = rowbase + (e & 3) + 8 * (e >> 2) + 4 * l5;
            os[row * C_ + c2 * 32 + lm] = oc[c2][e];
        }
#pragma unroll
    for (int e = 0; e < 16; ++e) {
        int cl = (e & 3) + 8 * (e >> 2) + 4 * l5;
        float bvv = bv[128 + wid * 32 + cl];
#pragma unroll
        for (int nn = 0; nn < 4; ++nn)
            uA[(wid * 32 + cl) * VT_LD + nn * 32 + lm] = f2bf(vac1[nn][e] + bvv);
    }
    wg_barrier();   // vT1 visible (global stores keep draining)

    // ---------------- PV half1: out[:, 128:256) ----------------
#pragma unroll
    for (int c2 = 0; c2 < 4; ++c2) oc[c2] = zero16();
#pragma unroll
    for (int kt16 = 0; kt16 < 8; ++kt16) {
#pragma unroll
        for (int c2 = 0; c2 < 4; ++c2) {
            short8 vb = *reinterpret_cast<const short8*>(&uA[(c2 * 32 + lm) * VT_LD + kt16 * 16 + l5 * 8]);
            oc[c2] = MFMA32(pf[kt16], vb, oc[c2]);
        }
    }
#pragma unroll
    for (int c2 = 0; c2 < 4; ++c2)
#pragma unroll
        for (int e = 0; e < 16; ++e) {
            int row = rowbase + (e & 3) + 8 * (e >> 2) + 4 * l5;
            os[row * C_ + 128 + c2 * 32 + lm] = oc[c2][e];
        }
}

extern "C" void kernel_launch(void* const* d_in, const int* in_sizes, int n_in,
                              void* d_out, int out_size, void* d_ws, size_t ws_size,
                              hipStream_t stream) {
    const float* x  = (const float*)d_in[0];
    const float* wq = (const float*)d_in[1];
    const float* bq = (const float*)d_in[2];
    const float* wk = (const float*)d_in[3];
    const float* bk = (const float*)d_in[4];
    const float* wv = (const float*)d_in[5];
    const float* bv = (const float*)d_in[6];
    float* out = (float*)d_out;
    u16* pack = (u16*)d_ws;   // 16 slabs x 5120 u16 = 160 KB

    prep_pack<<<320, 256, 0, stream>>>(wq, wk, wv, pack);
    attn_fused<<<2048, 256, 0, stream>>>(x, pack, bq, bk, bv, out);
}